// Round 9
// baseline (933.725 us; speedup 1.0000x reference)
//
#include <hip/hip_runtime.h>
#include <cmath>

// VQ-VAE quantization forward: B=64, K=1024, D=128, H=W=32.
// Ref model (6 rounds of absmax triangulation): q_k = fl32(fl32(A - fl32(2*B_k)) + C_k),
// first-index argmin, B = single-accumulator SEQUENTIAL FMA over d.
// A = sum(z*z,-1) sequential; C = sum(emb*emb,-1) pairwise-8.
// out0 = fl(fl(e-z)+z); out1 = e. Exact chains pinned with empty-asm barriers.
//
// R9: R8 (653us, absmax 0) is latency-bound with 1 block/CU (LDS 137KB) and
// 24.6M bank-conflict cycles from the z-transpose scalar writes. The z LDS
// tile only feeds one-time frag builds, rare refinement chains, and the
// epilogue — all readable from global (identical fp32 bits, L2-hot 32KB/block).
// Changes (feed/residency only, R8's verified coarse+selection untouched):
//  * s_zT DELETED. A-frags built from global z (32 scalar loads, once);
//    refinement A/B chains read z from global (same values, same order,
//    unroll-8 so independent loads pipeline under the pinned chain);
//    epilogue reads z from global (per-d 256B coalesced).
//  * LDS -> ~37KB, __launch_bounds__(512,4) => 2 blocks/CU co-residency:
//    one block's barrier/latency stalls hide under the other's compute.
//  * Transpose bank conflicts (16-way) and epilogue LDS read conflicts gone.
// Verbatim from R8: fragment bijection (l&15=code, l>>4=d-slice), C/D map
// col=lane&15(code) row=(lane>>4)*4+reg(px), f2bf bits, staging dbuf, top-4
// per-column in-register selection, 16-lane shfl gmin, MARGIN=2e-3, packed
// (q,k) u64 min-combine, snorm pairwise-8 / A / B / epilogue pinned chains,
// first-index tie-break.

#define D_DIM   128
#define K_CODES 1024
#define HW_SZ   1024
#define N_PIX   65536
#define OUT_OFF ((size_t)N_PIX * D_DIM)

#define PXB     128                     // pixels per block
#define NW      8                       // waves per block
#define NTILE   (K_CODES / 16)          // 64 code-tiles
#define TPR     4                       // tiles staged per round
#define ROUNDS  (NTILE / TPR)           // 16
#define NK      4                       // top-list depth per column per px-row
#define MARGIN  2.0e-3f                 // coarse->exact window

typedef float  f32x4 __attribute__((ext_vector_type(4)));
typedef short  s16x8 __attribute__((ext_vector_type(8)));
typedef unsigned short u16x8 __attribute__((ext_vector_type(8)));

// --- compiler-proof fp32 ops: result pinned in a VGPR via empty asm ---
__device__ __forceinline__ float fmul_x(float a, float b) {
    float r = a * b; asm volatile("" : "+v"(r)); return r;
}
__device__ __forceinline__ float fadd_x(float a, float b) {
    float r = a + b; asm volatile("" : "+v"(r)); return r;
}
__device__ __forceinline__ float fsub_x(float a, float b) {
    float r = a - b; asm volatile("" : "+v"(r)); return r;
}
__device__ __forceinline__ float ffma_x(float a, float b, float c) {
    float r = fmaf(a, b, c); asm volatile("" : "+v"(r)); return r;
}

// RNE float -> bf16 bits (inputs are normal floats here)
__device__ __forceinline__ unsigned short f2bf(float f) {
    unsigned u = __float_as_uint(f);
    u += 0x7FFFu + ((u >> 16) & 1u);
    return (unsigned short)(u >> 16);
}

// Stage TPR tiles (Tbase..Tbase+3) into dst in fragment order:
// dst[((tt*4 + dt)*64 + l)*8 + j] = bf16(emb[(Tbase+tt)*16 + (l&15)][dt*32 + ((l>>4)&3)*8 + j])
__device__ __forceinline__ void stage_tiles(
    const float* __restrict__ emb, unsigned short* __restrict__ dst,
    const int Tbase, const int tid)
{
    #pragma unroll
    for (int h = 0; h < 2; ++h) {
        const int f  = h * 512 + tid;        // fragment id 0..1023
        const int tt = f >> 8;               // tile within round
        const int dt = (f >> 6) & 3;         // d-block
        const int l  = f & 63;               // fragment lane
        const int code = (Tbase + tt) * 16 + (l & 15);
        const int d0   = dt * 32 + ((l >> 4) & 3) * 8;
        const float* src = emb + (size_t)code * D_DIM + d0;
        const f32x4 a = *(const f32x4*)(src);
        const f32x4 b = *(const f32x4*)(src + 4);
        u16x8 o;
        o[0] = f2bf(a[0]); o[1] = f2bf(a[1]); o[2] = f2bf(a[2]); o[3] = f2bf(a[3]);
        o[4] = f2bf(b[0]); o[5] = f2bf(b[1]); o[6] = f2bf(b[2]); o[7] = f2bf(b[3]);
        *(u16x8*)(dst + (size_t)f * 8) = o;
    }
}

__global__ __launch_bounds__(512, 4) void vq_fused(
    const float* __restrict__ z_e,
    const float* __restrict__ emb,
    float* __restrict__ out)
{
#pragma clang fp contract(off)
    __shared__ alignas(16) unsigned short e_s[2][TPR * 2048]; // 32768 B frag dbuf
    __shared__ float snorm[K_CODES];                          // 4096 B
    __shared__ int   s_kwin[PXB];                             // 512 B
    // total ~37 KB => 2 blocks/CU

    const int px  = threadIdx.x;                // lane 0..63
    const int ky  = threadIdx.y;                // wave 0..7
    const int tid = ky * 64 + px;

    const int p0  = blockIdx.x * PXB;
    const int b   = p0 >> 10;
    const int hw0 = p0 & (HW_SZ - 1);
    const float* zblk = z_e + (size_t)b * (D_DIM * HW_SZ) + hw0;

    // ---- C_k = np.sum(emb*emb,-1): pairwise-8 (n=128), chain verbatim ----
    for (int k = tid; k < K_CODES; k += NW * 64) {
        const float* row = emb + (size_t)k * D_DIM;
        float r[8];
        #pragma unroll
        for (int j = 0; j < 8; ++j) r[j] = fmul_x(row[j], row[j]);
        for (int i = 8; i < D_DIM; i += 8) {
            #pragma unroll
            for (int j = 0; j < 8; ++j)
                r[j] = fadd_x(r[j], fmul_x(row[i + j], row[i + j]));
        }
        const float s01 = fadd_x(r[0], r[1]), s23 = fadd_x(r[2], r[3]);
        const float s45 = fadd_x(r[4], r[5]), s67 = fadd_x(r[6], r[7]);
        snorm[k] = fadd_x(fadd_x(s01, s23), fadd_x(s45, s67));
    }

    // ---- round-0 e-frags ----
    stage_tiles(emb, e_s[0], 0, tid);

    // ---- build A-frags from GLOBAL z (once): wave ky owns px rows
    //      [ky*16, ky*16+16); lane reads its own column of z ----
    const int lm = px & 15;                     // 16-index (A row / B col)
    const int lg = px >> 4;                     // d-slice group 0..3
    const int pxbase = ky * 16;

    const float* zcol = zblk + (pxbase + lm);   // this lane's pixel column
    s16x8 afr[4];
    #pragma unroll
    for (int dt = 0; dt < 4; ++dt) {
        s16x8 a;
        #pragma unroll
        for (int j = 0; j < 8; ++j) {
            const int d = dt * 32 + lg * 8 + j;
            a[j] = (short)f2bf(zcol[(size_t)d * HW_SZ]);
        }
        afr[dt] = a;
    }

    __syncthreads();                            // snorm + round-0 frags visible

    // per-(px-row, column) 4-deep top lists, all indices compile-time constant
    float ct[4][NK]; int ck[4][NK];
    #pragma unroll
    for (int r = 0; r < 4; ++r) {
        #pragma unroll
        for (int s = 0; s < NK; ++s) { ct[r][s] = __builtin_inff(); ck[r][s] = 0; }
    }

    // ====== single coarse pass: MFMA scores + in-register selection ======
    {
        int buf = 0;
        #pragma unroll 1
        for (int rnd = 0; rnd < ROUNDS; ++rnd) {
            if (rnd + 1 < ROUNDS)
                stage_tiles(emb, e_s[buf ^ 1], (rnd + 1) * TPR, tid);
            #pragma unroll
            for (int tl = 0; tl < TPR; ++tl) {
                const unsigned short* fb = e_s[buf] + (size_t)tl * 2048 + (size_t)px * 8;
                const s16x8 c0 = *(const s16x8*)(fb);
                const s16x8 c1 = *(const s16x8*)(fb + 512);
                const s16x8 c2 = *(const s16x8*)(fb + 1024);
                const s16x8 c3 = *(const s16x8*)(fb + 1536);
                f32x4 a0 = {0.f, 0.f, 0.f, 0.f};
                f32x4 a1 = {0.f, 0.f, 0.f, 0.f};
                a0 = __builtin_amdgcn_mfma_f32_16x16x32_bf16(afr[0], c0, a0, 0, 0, 0);
                a0 = __builtin_amdgcn_mfma_f32_16x16x32_bf16(afr[1], c1, a0, 0, 0, 0);
                a1 = __builtin_amdgcn_mfma_f32_16x16x32_bf16(afr[2], c2, a1, 0, 0, 0);
                a1 = __builtin_amdgcn_mfma_f32_16x16x32_bf16(afr[3], c3, a1, 0, 0, 0);
                const int code = (rnd * TPR + tl) * 16 + lm;
                const float sn = snorm[code];
                #pragma unroll
                for (int r = 0; r < 4; ++r) {
                    const float t = fmaf(-2.f, a0[r] + a1[r], sn);
                    if (t < ct[r][3]) {
                        if (t < ct[r][1]) {
                            ct[r][3] = ct[r][2]; ck[r][3] = ck[r][2];
                            ct[r][2] = ct[r][1]; ck[r][2] = ck[r][1];
                            if (t < ct[r][0]) {
                                ct[r][1] = ct[r][0]; ck[r][1] = ck[r][0];
                                ct[r][0] = t; ck[r][0] = code;
                            } else { ct[r][1] = t; ck[r][1] = code; }
                        } else {
                            if (t < ct[r][2]) {
                                ct[r][3] = ct[r][2]; ck[r][3] = ck[r][2];
                                ct[r][2] = t; ck[r][2] = code;
                            } else { ct[r][3] = t; ck[r][3] = code; }
                        }
                    }
                }
            }
            __syncthreads();                    // next buf staged; this buf free
            buf ^= 1;
        }
    }

    // ---- gmin per pixel row via 16-lane shfl (masks stay in-group) ----
    float gmin[4];
    #pragma unroll
    for (int r = 0; r < 4; ++r) {
        gmin[r] = ct[r][0];
        #pragma unroll
        for (int mask = 1; mask < 16; mask <<= 1)
            gmin[r] = fminf(gmin[r], __shfl_xor(gmin[r], mask, 64));
    }

    // ---- per-lane exact refinement of qualifying candidates + u64 combine ----
    #pragma unroll 1
    for (int r = 0; r < 4; ++r) {
        const int prow = pxbase + lg * 4 + r;
        const float thr = gmin[r] + MARGIN;
        unsigned long long pack = ~0ULL;
        bool any = false;
        #pragma unroll
        for (int s = 0; s < NK; ++s) any = any || (ct[r][s] <= thr);
        if (any) {
            const float* zrow = zblk + prow;    // lane's pixel, global fp32 z
            // A: sequential over d (chain kept honest; value cancels per-pixel).
            const float z0 = zrow[0];
            float A32 = fmul_x(z0, z0);
            #pragma unroll 8
            for (int d = 1; d < D_DIM; ++d) {
                const float zd = zrow[(size_t)d * HW_SZ];
                A32 = fadd_x(A32, fmul_x(zd, zd));
            }
            #pragma unroll 1
            for (int s = 0; s < NK; ++s) {
                if (ct[r][s] <= thr) {
                    const int kc = ck[r][s];
                    const float* e = emb + (size_t)kc * D_DIM;
                    // B: GEMM-style single-accumulator SEQUENTIAL FMA over d.
                    float B32 = 0.f;
                    #pragma unroll 8
                    for (int d = 0; d < D_DIM; ++d)
                        B32 = ffma_x(zrow[(size_t)d * HW_SZ], e[d], B32);
                    const float twoB = fmul_x(2.0f, B32);      // exact
                    const float q    = fadd_x(fsub_x(A32, twoB), snorm[kc]);
                    // q = ||z-e||^2 ~ ||z||^2 > 0: positive-float uint order OK.
                    const unsigned long long p =
                        ((unsigned long long)__float_as_uint(q) << 32) |
                        (unsigned)kc;          // low bits = k: first-index tie-break
                    pack = (p < pack) ? p : pack;
                }
            }
        }
        // convergent 16-lane min-combine of packed (q,k)
        #pragma unroll
        for (int mask = 1; mask < 16; mask <<= 1) {
            const unsigned long long o = __shfl_xor(pack, mask, 64);
            pack = (o < pack) ? o : pack;
        }
        if (lm == 0) s_kwin[prow] = (int)(pack & 0xffffffffu);
    }
    __syncthreads();

    // ---- epilogue: out0 = fl(fl(e-z)+z) (pinned), out1 = e; z from global ----
    const int p  = tid & 127;                   // pixel
    const int dg = tid >> 7;                    // d-quarter 0..3
    const int kwin = s_kwin[p];
    const float* er = emb + (size_t)kwin * D_DIM + dg * 32;
    const float* zp = zblk + p;
    float* o0 = out + (size_t)b * (D_DIM * HW_SZ) + hw0 + p;
    float* o1 = o0 + OUT_OFF;
    #pragma unroll
    for (int i = 0; i < 8; ++i) {
        const f32x4 e4 = *(const f32x4*)(er + i * 4);
        #pragma unroll
        for (int j = 0; j < 4; ++j) {
            const int d = dg * 32 + i * 4 + j;
            const float zv = zp[(size_t)d * HW_SZ];
            o0[(size_t)d * HW_SZ] = fadd_x(fsub_x(e4[j], zv), zv);
            o1[(size_t)d * HW_SZ] = e4[j];
        }
    }
}

extern "C" void kernel_launch(void* const* d_in, const int* in_sizes, int n_in,
                              void* d_out, int out_size, void* d_ws, size_t ws_size,
                              hipStream_t stream)
{
    const float* z_e = (const float*)d_in[0];
    const float* emb = (const float*)d_in[1];
    float* out = (float*)d_out;
    (void)in_sizes; (void)n_in; (void)out_size; (void)d_ws; (void)ws_size;

    vq_fused<<<dim3(N_PIX / PXB), dim3(64, NW), 0, stream>>>(z_e, emb, out);
}

// Round 10
// 930.603 us; speedup vs baseline: 1.0034x; 1.0034x over previous
//
#include <hip/hip_runtime.h>
#include <cmath>

// VQ-VAE quantization forward: B=64, K=1024, D=128, H=W=32.
// Ref model (6 rounds of absmax triangulation): q_k = fl32(fl32(A - fl32(2*B_k)) + C_k),
// first-index argmin, B = single-accumulator SEQUENTIAL FMA over d.
// A = sum(z*z,-1) sequential; C = sum(emb*emb,-1) pairwise-8.
// out0 = fl(fl(e-z)+z); out1 = e. Exact chains pinned with empty-asm barriers.
//
// R10 = R9 with ONLY __launch_bounds__(512,4) -> (512,2). R9's regression was
// pure spill: (512,4) drove the VGPR target to 44 (< ~60 live set) => coarse-
// loop state spilled to HBM-backed scratch (FETCH 200MB, WRITE 780MB = 6x
// output, 1.0GB at 1.1TB/s = the whole 900us). Empirical compiler rule from
// R1/R2/R8/R9: min-waves/EU > 2 triggers an aggressive sub-live-set cap;
// (512,2) gives 80-88 VGPR, zero spill. With actual use ~88 <= 128 and LDS
// 37KB, hardware still co-resides 2 blocks/CU (R9 measured 43% occupancy) —
// now without the spill tax. R9's verified wins kept: s_zT deleted (bank
// conflicts 24.6M -> 2.5K), z read from global (identical fp32 bits), 37KB
// LDS footprint.
// Verbatim from R8: fragment bijection (l&15=code, l>>4=d-slice), C/D map
// col=lane&15(code) row=(lane>>4)*4+reg(px), f2bf bits, staging dbuf, top-4
// per-column in-register selection, 16-lane shfl gmin, MARGIN=2e-3, packed
// (q,k) u64 min-combine, snorm pairwise-8 / A / B / epilogue pinned chains,
// first-index tie-break.

#define D_DIM   128
#define K_CODES 1024
#define HW_SZ   1024
#define N_PIX   65536
#define OUT_OFF ((size_t)N_PIX * D_DIM)

#define PXB     128                     // pixels per block
#define NW      8                       // waves per block
#define NTILE   (K_CODES / 16)          // 64 code-tiles
#define TPR     4                       // tiles staged per round
#define ROUNDS  (NTILE / TPR)           // 16
#define NK      4                       // top-list depth per column per px-row
#define MARGIN  2.0e-3f                 // coarse->exact window

typedef float  f32x4 __attribute__((ext_vector_type(4)));
typedef short  s16x8 __attribute__((ext_vector_type(8)));
typedef unsigned short u16x8 __attribute__((ext_vector_type(8)));

// --- compiler-proof fp32 ops: result pinned in a VGPR via empty asm ---
__device__ __forceinline__ float fmul_x(float a, float b) {
    float r = a * b; asm volatile("" : "+v"(r)); return r;
}
__device__ __forceinline__ float fadd_x(float a, float b) {
    float r = a + b; asm volatile("" : "+v"(r)); return r;
}
__device__ __forceinline__ float fsub_x(float a, float b) {
    float r = a - b; asm volatile("" : "+v"(r)); return r;
}
__device__ __forceinline__ float ffma_x(float a, float b, float c) {
    float r = fmaf(a, b, c); asm volatile("" : "+v"(r)); return r;
}

// RNE float -> bf16 bits (inputs are normal floats here)
__device__ __forceinline__ unsigned short f2bf(float f) {
    unsigned u = __float_as_uint(f);
    u += 0x7FFFu + ((u >> 16) & 1u);
    return (unsigned short)(u >> 16);
}

// Stage TPR tiles (Tbase..Tbase+3) into dst in fragment order:
// dst[((tt*4 + dt)*64 + l)*8 + j] = bf16(emb[(Tbase+tt)*16 + (l&15)][dt*32 + ((l>>4)&3)*8 + j])
__device__ __forceinline__ void stage_tiles(
    const float* __restrict__ emb, unsigned short* __restrict__ dst,
    const int Tbase, const int tid)
{
    #pragma unroll
    for (int h = 0; h < 2; ++h) {
        const int f  = h * 512 + tid;        // fragment id 0..1023
        const int tt = f >> 8;               // tile within round
        const int dt = (f >> 6) & 3;         // d-block
        const int l  = f & 63;               // fragment lane
        const int code = (Tbase + tt) * 16 + (l & 15);
        const int d0   = dt * 32 + ((l >> 4) & 3) * 8;
        const float* src = emb + (size_t)code * D_DIM + d0;
        const f32x4 a = *(const f32x4*)(src);
        const f32x4 b = *(const f32x4*)(src + 4);
        u16x8 o;
        o[0] = f2bf(a[0]); o[1] = f2bf(a[1]); o[2] = f2bf(a[2]); o[3] = f2bf(a[3]);
        o[4] = f2bf(b[0]); o[5] = f2bf(b[1]); o[6] = f2bf(b[2]); o[7] = f2bf(b[3]);
        *(u16x8*)(dst + (size_t)f * 8) = o;
    }
}

__global__ __launch_bounds__(512, 2) void vq_fused(
    const float* __restrict__ z_e,
    const float* __restrict__ emb,
    float* __restrict__ out)
{
#pragma clang fp contract(off)
    __shared__ alignas(16) unsigned short e_s[2][TPR * 2048]; // 32768 B frag dbuf
    __shared__ float snorm[K_CODES];                          // 4096 B
    __shared__ int   s_kwin[PXB];                             // 512 B
    // total ~37 KB => hardware can co-reside 2+ blocks/CU (VGPR-permitting)

    const int px  = threadIdx.x;                // lane 0..63
    const int ky  = threadIdx.y;                // wave 0..7
    const int tid = ky * 64 + px;

    const int p0  = blockIdx.x * PXB;
    const int b   = p0 >> 10;
    const int hw0 = p0 & (HW_SZ - 1);
    const float* zblk = z_e + (size_t)b * (D_DIM * HW_SZ) + hw0;

    // ---- C_k = np.sum(emb*emb,-1): pairwise-8 (n=128), chain verbatim ----
    for (int k = tid; k < K_CODES; k += NW * 64) {
        const float* row = emb + (size_t)k * D_DIM;
        float r[8];
        #pragma unroll
        for (int j = 0; j < 8; ++j) r[j] = fmul_x(row[j], row[j]);
        for (int i = 8; i < D_DIM; i += 8) {
            #pragma unroll
            for (int j = 0; j < 8; ++j)
                r[j] = fadd_x(r[j], fmul_x(row[i + j], row[i + j]));
        }
        const float s01 = fadd_x(r[0], r[1]), s23 = fadd_x(r[2], r[3]);
        const float s45 = fadd_x(r[4], r[5]), s67 = fadd_x(r[6], r[7]);
        snorm[k] = fadd_x(fadd_x(s01, s23), fadd_x(s45, s67));
    }

    // ---- round-0 e-frags ----
    stage_tiles(emb, e_s[0], 0, tid);

    // ---- build A-frags from GLOBAL z (once): wave ky owns px rows
    //      [ky*16, ky*16+16); lane reads its own column of z ----
    const int lm = px & 15;                     // 16-index (A row / B col)
    const int lg = px >> 4;                     // d-slice group 0..3
    const int pxbase = ky * 16;

    const float* zcol = zblk + (pxbase + lm);   // this lane's pixel column
    s16x8 afr[4];
    #pragma unroll
    for (int dt = 0; dt < 4; ++dt) {
        s16x8 a;
        #pragma unroll
        for (int j = 0; j < 8; ++j) {
            const int d = dt * 32 + lg * 8 + j;
            a[j] = (short)f2bf(zcol[(size_t)d * HW_SZ]);
        }
        afr[dt] = a;
    }

    __syncthreads();                            // snorm + round-0 frags visible

    // per-(px-row, column) 4-deep top lists, all indices compile-time constant
    float ct[4][NK]; int ck[4][NK];
    #pragma unroll
    for (int r = 0; r < 4; ++r) {
        #pragma unroll
        for (int s = 0; s < NK; ++s) { ct[r][s] = __builtin_inff(); ck[r][s] = 0; }
    }

    // ====== single coarse pass: MFMA scores + in-register selection ======
    {
        int buf = 0;
        #pragma unroll 1
        for (int rnd = 0; rnd < ROUNDS; ++rnd) {
            if (rnd + 1 < ROUNDS)
                stage_tiles(emb, e_s[buf ^ 1], (rnd + 1) * TPR, tid);
            #pragma unroll
            for (int tl = 0; tl < TPR; ++tl) {
                const unsigned short* fb = e_s[buf] + (size_t)tl * 2048 + (size_t)px * 8;
                const s16x8 c0 = *(const s16x8*)(fb);
                const s16x8 c1 = *(const s16x8*)(fb + 512);
                const s16x8 c2 = *(const s16x8*)(fb + 1024);
                const s16x8 c3 = *(const s16x8*)(fb + 1536);
                f32x4 a0 = {0.f, 0.f, 0.f, 0.f};
                f32x4 a1 = {0.f, 0.f, 0.f, 0.f};
                a0 = __builtin_amdgcn_mfma_f32_16x16x32_bf16(afr[0], c0, a0, 0, 0, 0);
                a0 = __builtin_amdgcn_mfma_f32_16x16x32_bf16(afr[1], c1, a0, 0, 0, 0);
                a1 = __builtin_amdgcn_mfma_f32_16x16x32_bf16(afr[2], c2, a1, 0, 0, 0);
                a1 = __builtin_amdgcn_mfma_f32_16x16x32_bf16(afr[3], c3, a1, 0, 0, 0);
                const int code = (rnd * TPR + tl) * 16 + lm;
                const float sn = snorm[code];
                #pragma unroll
                for (int r = 0; r < 4; ++r) {
                    const float t = fmaf(-2.f, a0[r] + a1[r], sn);
                    if (t < ct[r][3]) {
                        if (t < ct[r][1]) {
                            ct[r][3] = ct[r][2]; ck[r][3] = ck[r][2];
                            ct[r][2] = ct[r][1]; ck[r][2] = ck[r][1];
                            if (t < ct[r][0]) {
                                ct[r][1] = ct[r][0]; ck[r][1] = ck[r][0];
                                ct[r][0] = t; ck[r][0] = code;
                            } else { ct[r][1] = t; ck[r][1] = code; }
                        } else {
                            if (t < ct[r][2]) {
                                ct[r][3] = ct[r][2]; ck[r][3] = ck[r][2];
                                ct[r][2] = t; ck[r][2] = code;
                            } else { ct[r][3] = t; ck[r][3] = code; }
                        }
                    }
                }
            }
            __syncthreads();                    // next buf staged; this buf free
            buf ^= 1;
        }
    }

    // ---- gmin per pixel row via 16-lane shfl (masks stay in-group) ----
    float gmin[4];
    #pragma unroll
    for (int r = 0; r < 4; ++r) {
        gmin[r] = ct[r][0];
        #pragma unroll
        for (int mask = 1; mask < 16; mask <<= 1)
            gmin[r] = fminf(gmin[r], __shfl_xor(gmin[r], mask, 64));
    }

    // ---- per-lane exact refinement of qualifying candidates + u64 combine ----
    #pragma unroll 1
    for (int r = 0; r < 4; ++r) {
        const int prow = pxbase + lg * 4 + r;
        const float thr = gmin[r] + MARGIN;
        unsigned long long pack = ~0ULL;
        bool any = false;
        #pragma unroll
        for (int s = 0; s < NK; ++s) any = any || (ct[r][s] <= thr);
        if (any) {
            const float* zrow = zblk + prow;    // lane's pixel, global fp32 z
            // A: sequential over d (chain kept honest; value cancels per-pixel).
            const float z0 = zrow[0];
            float A32 = fmul_x(z0, z0);
            #pragma unroll 8
            for (int d = 1; d < D_DIM; ++d) {
                const float zd = zrow[(size_t)d * HW_SZ];
                A32 = fadd_x(A32, fmul_x(zd, zd));
            }
            #pragma unroll 1
            for (int s = 0; s < NK; ++s) {
                if (ct[r][s] <= thr) {
                    const int kc = ck[r][s];
                    const float* e = emb + (size_t)kc * D_DIM;
                    // B: GEMM-style single-accumulator SEQUENTIAL FMA over d.
                    float B32 = 0.f;
                    #pragma unroll 8
                    for (int d = 0; d < D_DIM; ++d)
                        B32 = ffma_x(zrow[(size_t)d * HW_SZ], e[d], B32);
                    const float twoB = fmul_x(2.0f, B32);      // exact
                    const float q    = fadd_x(fsub_x(A32, twoB), snorm[kc]);
                    // q = ||z-e||^2 ~ ||z||^2 > 0: positive-float uint order OK.
                    const unsigned long long p =
                        ((unsigned long long)__float_as_uint(q) << 32) |
                        (unsigned)kc;          // low bits = k: first-index tie-break
                    pack = (p < pack) ? p : pack;
                }
            }
        }
        // convergent 16-lane min-combine of packed (q,k)
        #pragma unroll
        for (int mask = 1; mask < 16; mask <<= 1) {
            const unsigned long long o = __shfl_xor(pack, mask, 64);
            pack = (o < pack) ? o : pack;
        }
        if (lm == 0) s_kwin[prow] = (int)(pack & 0xffffffffu);
    }
    __syncthreads();

    // ---- epilogue: out0 = fl(fl(e-z)+z) (pinned), out1 = e; z from global ----
    const int p  = tid & 127;                   // pixel
    const int dg = tid >> 7;                    // d-quarter 0..3
    const int kwin = s_kwin[p];
    const float* er = emb + (size_t)kwin * D_DIM + dg * 32;
    const float* zp = zblk + p;
    float* o0 = out + (size_t)b * (D_DIM * HW_SZ) + hw0 + p;
    float* o1 = o0 + OUT_OFF;
    #pragma unroll
    for (int i = 0; i < 8; ++i) {
        const f32x4 e4 = *(const f32x4*)(er + i * 4);
        #pragma unroll
        for (int j = 0; j < 4; ++j) {
            const int d = dg * 32 + i * 4 + j;
            const float zv = zp[(size_t)d * HW_SZ];
            o0[(size_t)d * HW_SZ] = fadd_x(fsub_x(e4[j], zv), zv);
            o1[(size_t)d * HW_SZ] = e4[j];
        }
    }
}

extern "C" void kernel_launch(void* const* d_in, const int* in_sizes, int n_in,
                              void* d_out, int out_size, void* d_ws, size_t ws_size,
                              hipStream_t stream)
{
    const float* z_e = (const float*)d_in[0];
    const float* emb = (const float*)d_in[1];
    float* out = (float*)d_out;
    (void)in_sizes; (void)n_in; (void)out_size; (void)d_ws; (void)ws_size;

    vq_fused<<<dim3(N_PIX / PXB), dim3(64, NW), 0, stream>>>(z_e, emb, out);
}

// Round 11
// 814.650 us; speedup vs baseline: 1.1462x; 1.1423x over previous
//
#include <hip/hip_runtime.h>
#include <cmath>

// VQ-VAE quantization forward: B=64, K=1024, D=128, H=W=32.
// Ref model (6 rounds of absmax triangulation): q_k = fl32(fl32(A - fl32(2*B_k)) + C_k),
// first-index argmin, B = single-accumulator SEQUENTIAL FMA over d.
// A = sum(z*z,-1) sequential; C = sum(emb*emb,-1) pairwise-8.
// out0 = fl(fl(e-z)+z); out1 = e. Exact chains pinned with empty-asm barriers.
//
// R11 = R10 body byte-for-byte; only the occupancy-control changes. R9/R10
// proved the spill is LDS-DRIVEN, not launch-bounds-driven: (512,4) and
// (512,2) both gave VGPR=44 + 750MB scratch at 37KB LDS, while R8's 137KB
// LDS gave VGPR=88 clean with identical bounds. The AMDGPU backend ties the
// RA register budget to LDS-implied occupancy (37KB => 4 blk/CU => 8 waves/EU
// => ~64-reg cap => spill below the ~90 live set). Two explicit clamps:
//  * __attribute__((amdgpu_waves_per_eu(2,4))): RA budget 512/4 = 128 regs.
//  * LDS padded to ~66.5KB: LDS-implied occupancy itself becomes 2 blk/CU
//    (= 4 waves/EU), reproducing R8's proven generous-RA regime while keeping
//    the 2-block co-residency R9/R10 measured (43% occupancy).
// Verbatim from R8-R10: fragment bijection (l&15=code, l>>4=d-slice), C/D map
// col=lane&15(code) row=(lane>>4)*4+reg(px), f2bf bits, staging dbuf, top-4
// per-column in-register selection, 16-lane shfl gmin, MARGIN=2e-3, packed
// (q,k) u64 min-combine, snorm pairwise-8 / A / B / epilogue pinned chains,
// first-index tie-break, z from global (identical fp32 bits).

#define D_DIM   128
#define K_CODES 1024
#define HW_SZ   1024
#define N_PIX   65536
#define OUT_OFF ((size_t)N_PIX * D_DIM)

#define PXB     128                     // pixels per block
#define NW      8                       // waves per block
#define NTILE   (K_CODES / 16)          // 64 code-tiles
#define TPR     4                       // tiles staged per round
#define ROUNDS  (NTILE / TPR)           // 16
#define NK      4                       // top-list depth per column per px-row
#define MARGIN  2.0e-3f                 // coarse->exact window
#define PADF    7296                    // LDS pad -> ~66.5KB total => 2 blk/CU cap

typedef float  f32x4 __attribute__((ext_vector_type(4)));
typedef short  s16x8 __attribute__((ext_vector_type(8)));
typedef unsigned short u16x8 __attribute__((ext_vector_type(8)));

// --- compiler-proof fp32 ops: result pinned in a VGPR via empty asm ---
__device__ __forceinline__ float fmul_x(float a, float b) {
    float r = a * b; asm volatile("" : "+v"(r)); return r;
}
__device__ __forceinline__ float fadd_x(float a, float b) {
    float r = a + b; asm volatile("" : "+v"(r)); return r;
}
__device__ __forceinline__ float fsub_x(float a, float b) {
    float r = a - b; asm volatile("" : "+v"(r)); return r;
}
__device__ __forceinline__ float ffma_x(float a, float b, float c) {
    float r = fmaf(a, b, c); asm volatile("" : "+v"(r)); return r;
}

// RNE float -> bf16 bits (inputs are normal floats here)
__device__ __forceinline__ unsigned short f2bf(float f) {
    unsigned u = __float_as_uint(f);
    u += 0x7FFFu + ((u >> 16) & 1u);
    return (unsigned short)(u >> 16);
}

// Stage TPR tiles (Tbase..Tbase+3) into dst in fragment order:
// dst[((tt*4 + dt)*64 + l)*8 + j] = bf16(emb[(Tbase+tt)*16 + (l&15)][dt*32 + ((l>>4)&3)*8 + j])
__device__ __forceinline__ void stage_tiles(
    const float* __restrict__ emb, unsigned short* __restrict__ dst,
    const int Tbase, const int tid)
{
    #pragma unroll
    for (int h = 0; h < 2; ++h) {
        const int f  = h * 512 + tid;        // fragment id 0..1023
        const int tt = f >> 8;               // tile within round
        const int dt = (f >> 6) & 3;         // d-block
        const int l  = f & 63;               // fragment lane
        const int code = (Tbase + tt) * 16 + (l & 15);
        const int d0   = dt * 32 + ((l >> 4) & 3) * 8;
        const float* src = emb + (size_t)code * D_DIM + d0;
        const f32x4 a = *(const f32x4*)(src);
        const f32x4 b = *(const f32x4*)(src + 4);
        u16x8 o;
        o[0] = f2bf(a[0]); o[1] = f2bf(a[1]); o[2] = f2bf(a[2]); o[3] = f2bf(a[3]);
        o[4] = f2bf(b[0]); o[5] = f2bf(b[1]); o[6] = f2bf(b[2]); o[7] = f2bf(b[3]);
        *(u16x8*)(dst + (size_t)f * 8) = o;
    }
}

__global__ __attribute__((amdgpu_flat_work_group_size(512, 512),
                          amdgpu_waves_per_eu(2, 4)))
void vq_fused(
    const float* __restrict__ z_e,
    const float* __restrict__ emb,
    float* __restrict__ out)
{
#pragma clang fp contract(off)
    __shared__ alignas(16) unsigned short e_s[2][TPR * 2048]; // 32768 B frag dbuf
    __shared__ float snorm[K_CODES];                          // 4096 B
    __shared__ int   s_kwin[PXB];                             // 512 B
    __shared__ float s_pad[PADF];                             // 29184 B occupancy governor
    // total ~66.5 KB => LDS-implied cap = 2 blocks/CU (4 waves/EU)

    const int px  = threadIdx.x;                // lane 0..63
    const int ky  = threadIdx.y;                // wave 0..7
    const int tid = ky * 64 + px;

    // keep the pad alive without measurable cost
    s_pad[tid] = 0.f;

    const int p0  = blockIdx.x * PXB;
    const int b   = p0 >> 10;
    const int hw0 = p0 & (HW_SZ - 1);
    const float* zblk = z_e + (size_t)b * (D_DIM * HW_SZ) + hw0;

    // ---- C_k = np.sum(emb*emb,-1): pairwise-8 (n=128), chain verbatim ----
    for (int k = tid; k < K_CODES; k += NW * 64) {
        const float* row = emb + (size_t)k * D_DIM;
        float r[8];
        #pragma unroll
        for (int j = 0; j < 8; ++j) r[j] = fmul_x(row[j], row[j]);
        for (int i = 8; i < D_DIM; i += 8) {
            #pragma unroll
            for (int j = 0; j < 8; ++j)
                r[j] = fadd_x(r[j], fmul_x(row[i + j], row[i + j]));
        }
        const float s01 = fadd_x(r[0], r[1]), s23 = fadd_x(r[2], r[3]);
        const float s45 = fadd_x(r[4], r[5]), s67 = fadd_x(r[6], r[7]);
        snorm[k] = fadd_x(fadd_x(s01, s23), fadd_x(s45, s67));
    }

    // ---- round-0 e-frags ----
    stage_tiles(emb, e_s[0], 0, tid);

    // ---- build A-frags from GLOBAL z (once): wave ky owns px rows
    //      [ky*16, ky*16+16); lane reads its own column of z ----
    const int lm = px & 15;                     // 16-index (A row / B col)
    const int lg = px >> 4;                     // d-slice group 0..3
    const int pxbase = ky * 16;

    const float* zcol = zblk + (pxbase + lm);   // this lane's pixel column
    s16x8 afr[4];
    #pragma unroll
    for (int dt = 0; dt < 4; ++dt) {
        s16x8 a;
        #pragma unroll
        for (int j = 0; j < 8; ++j) {
            const int d = dt * 32 + lg * 8 + j;
            a[j] = (short)f2bf(zcol[(size_t)d * HW_SZ]);
        }
        afr[dt] = a;
    }

    __syncthreads();                            // snorm + round-0 frags visible

    // per-(px-row, column) 4-deep top lists, all indices compile-time constant
    float ct[4][NK]; int ck[4][NK];
    #pragma unroll
    for (int r = 0; r < 4; ++r) {
        #pragma unroll
        for (int s = 0; s < NK; ++s) { ct[r][s] = __builtin_inff(); ck[r][s] = 0; }
    }

    // ====== single coarse pass: MFMA scores + in-register selection ======
    {
        int buf = 0;
        #pragma unroll 1
        for (int rnd = 0; rnd < ROUNDS; ++rnd) {
            if (rnd + 1 < ROUNDS)
                stage_tiles(emb, e_s[buf ^ 1], (rnd + 1) * TPR, tid);
            #pragma unroll
            for (int tl = 0; tl < TPR; ++tl) {
                const unsigned short* fb = e_s[buf] + (size_t)tl * 2048 + (size_t)px * 8;
                const s16x8 c0 = *(const s16x8*)(fb);
                const s16x8 c1 = *(const s16x8*)(fb + 512);
                const s16x8 c2 = *(const s16x8*)(fb + 1024);
                const s16x8 c3 = *(const s16x8*)(fb + 1536);
                f32x4 a0 = {0.f, 0.f, 0.f, 0.f};
                f32x4 a1 = {0.f, 0.f, 0.f, 0.f};
                a0 = __builtin_amdgcn_mfma_f32_16x16x32_bf16(afr[0], c0, a0, 0, 0, 0);
                a0 = __builtin_amdgcn_mfma_f32_16x16x32_bf16(afr[1], c1, a0, 0, 0, 0);
                a1 = __builtin_amdgcn_mfma_f32_16x16x32_bf16(afr[2], c2, a1, 0, 0, 0);
                a1 = __builtin_amdgcn_mfma_f32_16x16x32_bf16(afr[3], c3, a1, 0, 0, 0);
                const int code = (rnd * TPR + tl) * 16 + lm;
                const float sn = snorm[code];
                #pragma unroll
                for (int r = 0; r < 4; ++r) {
                    const float t = fmaf(-2.f, a0[r] + a1[r], sn);
                    if (t < ct[r][3]) {
                        if (t < ct[r][1]) {
                            ct[r][3] = ct[r][2]; ck[r][3] = ck[r][2];
                            ct[r][2] = ct[r][1]; ck[r][2] = ck[r][1];
                            if (t < ct[r][0]) {
                                ct[r][1] = ct[r][0]; ck[r][1] = ck[r][0];
                                ct[r][0] = t; ck[r][0] = code;
                            } else { ct[r][1] = t; ck[r][1] = code; }
                        } else {
                            if (t < ct[r][2]) {
                                ct[r][3] = ct[r][2]; ck[r][3] = ck[r][2];
                                ct[r][2] = t; ck[r][2] = code;
                            } else { ct[r][3] = t; ck[r][3] = code; }
                        }
                    }
                }
            }
            __syncthreads();                    // next buf staged; this buf free
            buf ^= 1;
        }
    }

    // ---- gmin per pixel row via 16-lane shfl (masks stay in-group) ----
    float gmin[4];
    #pragma unroll
    for (int r = 0; r < 4; ++r) {
        gmin[r] = ct[r][0];
        #pragma unroll
        for (int mask = 1; mask < 16; mask <<= 1)
            gmin[r] = fminf(gmin[r], __shfl_xor(gmin[r], mask, 64));
    }

    // ---- per-lane exact refinement of qualifying candidates + u64 combine ----
    #pragma unroll 1
    for (int r = 0; r < 4; ++r) {
        const int prow = pxbase + lg * 4 + r;
        const float thr = gmin[r] + MARGIN;
        unsigned long long pack = ~0ULL;
        bool any = false;
        #pragma unroll
        for (int s = 0; s < NK; ++s) any = any || (ct[r][s] <= thr);
        if (any) {
            const float* zrow = zblk + prow;    // lane's pixel, global fp32 z
            // A: sequential over d (chain kept honest; value cancels per-pixel).
            const float z0 = zrow[0];
            float A32 = fmul_x(z0, z0);
            #pragma unroll 8
            for (int d = 1; d < D_DIM; ++d) {
                const float zd = zrow[(size_t)d * HW_SZ];
                A32 = fadd_x(A32, fmul_x(zd, zd));
            }
            #pragma unroll 1
            for (int s = 0; s < NK; ++s) {
                if (ct[r][s] <= thr) {
                    const int kc = ck[r][s];
                    const float* e = emb + (size_t)kc * D_DIM;
                    // B: GEMM-style single-accumulator SEQUENTIAL FMA over d.
                    float B32 = 0.f;
                    #pragma unroll 8
                    for (int d = 0; d < D_DIM; ++d)
                        B32 = ffma_x(zrow[(size_t)d * HW_SZ], e[d], B32);
                    const float twoB = fmul_x(2.0f, B32);      // exact
                    const float q    = fadd_x(fsub_x(A32, twoB), snorm[kc]);
                    // q = ||z-e||^2 ~ ||z||^2 > 0: positive-float uint order OK.
                    const unsigned long long p =
                        ((unsigned long long)__float_as_uint(q) << 32) |
                        (unsigned)kc;          // low bits = k: first-index tie-break
                    pack = (p < pack) ? p : pack;
                }
            }
        }
        // convergent 16-lane min-combine of packed (q,k)
        #pragma unroll
        for (int mask = 1; mask < 16; mask <<= 1) {
            const unsigned long long o = __shfl_xor(pack, mask, 64);
            pack = (o < pack) ? o : pack;
        }
        if (lm == 0) s_kwin[prow] = (int)(pack & 0xffffffffu);
    }
    __syncthreads();

    // ---- epilogue: out0 = fl(fl(e-z)+z) (pinned), out1 = e; z from global ----
    const int p  = tid & 127;                   // pixel
    const int dg = tid >> 7;                    // d-quarter 0..3
    const int kwin = s_kwin[p];
    const float* er = emb + (size_t)kwin * D_DIM + dg * 32;
    const float* zp = zblk + p;
    float* o0 = out + (size_t)b * (D_DIM * HW_SZ) + hw0 + p;
    float* o1 = o0 + OUT_OFF;
    #pragma unroll
    for (int i = 0; i < 8; ++i) {
        const f32x4 e4 = *(const f32x4*)(er + i * 4);
        #pragma unroll
        for (int j = 0; j < 4; ++j) {
            const int d = dg * 32 + i * 4 + j;
            const float zv = zp[(size_t)d * HW_SZ];
            o0[(size_t)d * HW_SZ] = fadd_x(fsub_x(e4[j], zv), zv);
            o1[(size_t)d * HW_SZ] = e4[j];
        }
    }
}

extern "C" void kernel_launch(void* const* d_in, const int* in_sizes, int n_in,
                              void* d_out, int out_size, void* d_ws, size_t ws_size,
                              hipStream_t stream)
{
    const float* z_e = (const float*)d_in[0];
    const float* emb = (const float*)d_in[1];
    float* out = (float*)d_out;
    (void)in_sizes; (void)n_in; (void)out_size; (void)d_ws; (void)ws_size;

    vq_fused<<<dim3(N_PIX / PXB), dim3(64, NW), 0, stream>>>(z_e, emb, out);
}

// Round 12
// 526.384 us; speedup vs baseline: 1.7738x; 1.5476x over previous
//
#include <hip/hip_runtime.h>
#include <cmath>

// VQ-VAE quantization forward: B=64, K=1024, D=128, H=W=32.
// Ref model (6 rounds of absmax triangulation): q_k = fl32(fl32(A - fl32(2*B_k)) + C_k),
// first-index argmin, B = single-accumulator SEQUENTIAL FMA over d.
// A = sum(z*z,-1) sequential; C = sum(emb*emb,-1) pairwise-8.
// out0 = fl(fl(e-z)+z); out1 = e. Exact chains pinned with empty-asm barriers.
//
// R12 = R8-exact base (653us known-good: s_zT LDS tile, 137KB LDS => generous
// RA regime, VGPR 88 no spill) with the selection machinery replaced:
//  * R9-R11 proved the spill is allocator-behavior we cannot control via
//    launch bounds / waves_per_eu / LDS pads (44/44/52 VGPR across all three).
//    Only the big-LDS regime is measured spill-free. Stay in it.
//  * Coarse selection -> BRANCHLESS packed u32: key = monotone(t) top-22 bits
//    | code (10 bits). t ~ 1e-2 scale => truncation quantum ~4e-6, negligible
//    vs MARGIN=2e-3. Top-4 per column via 7-op min/max sorting network: no
//    divergent branch tree, no exec-mask churn, selection state 32->16 VGPRs.
//  * Refinement r-loop FULLY unrolled (all pk[r][s] indices compile-time) —
//    removes the runtime-indexed-array=>scratch hazard (rule #20).
// Verbatim from R8: fragment bijection (l&15=code, l>>4=d-slice), C/D map
// col=lane&15(code) row=(lane>>4)*4+reg(px), f2bf bits, staging dbuf, 16-lane
// shfl gmin, MARGIN=2e-3 window, exact pinned snorm/A/B/epilogue chains,
// packed (q,k) u64 min-combine, first-index tie-break.

#define D_DIM   128
#define K_CODES 1024
#define HW_SZ   1024
#define N_PIX   65536
#define OUT_OFF ((size_t)N_PIX * D_DIM)

#define PXB     128                     // pixels per block
#define NW      8                       // waves per block
#define NTILE   (K_CODES / 16)          // 64 code-tiles
#define TPR     4                       // tiles staged per round
#define ROUNDS  (NTILE / TPR)           // 16
#define ZLD     132                     // padded z row (floats)
#define MARGIN  2.0e-3f                 // coarse->exact window
#define KMASK   0xFFFFFC00u             // key bits (code in low 10)

typedef float  f32x4 __attribute__((ext_vector_type(4)));
typedef short  s16x8 __attribute__((ext_vector_type(8)));
typedef unsigned short u16x8 __attribute__((ext_vector_type(8)));

// --- compiler-proof fp32 ops: result pinned in a VGPR via empty asm ---
__device__ __forceinline__ float fmul_x(float a, float b) {
    float r = a * b; asm volatile("" : "+v"(r)); return r;
}
__device__ __forceinline__ float fadd_x(float a, float b) {
    float r = a + b; asm volatile("" : "+v"(r)); return r;
}
__device__ __forceinline__ float fsub_x(float a, float b) {
    float r = a - b; asm volatile("" : "+v"(r)); return r;
}
__device__ __forceinline__ float ffma_x(float a, float b, float c) {
    float r = fmaf(a, b, c); asm volatile("" : "+v"(r)); return r;
}

// RNE float -> bf16 bits (inputs are normal floats here)
__device__ __forceinline__ unsigned short f2bf(float f) {
    unsigned u = __float_as_uint(f);
    u += 0x7FFFu + ((u >> 16) & 1u);
    return (unsigned short)(u >> 16);
}

// monotone float<->u32 order-preserving transform (no NaNs in play)
__device__ __forceinline__ unsigned key32(float t) {
    const unsigned u = __float_as_uint(t);
    return u ^ (unsigned)(((int)u >> 31) | (int)0x80000000);
}
__device__ __forceinline__ float unkey32(unsigned k) {
    const unsigned u = (k & 0x80000000u) ? (k ^ 0x80000000u) : ~k;
    return __uint_as_float(u);
}

// Stage TPR tiles (Tbase..Tbase+3) into dst in fragment order:
// dst[((tt*4 + dt)*64 + l)*8 + j] = bf16(emb[(Tbase+tt)*16 + (l&15)][dt*32 + ((l>>4)&3)*8 + j])
__device__ __forceinline__ void stage_tiles(
    const float* __restrict__ emb, unsigned short* __restrict__ dst,
    const int Tbase, const int tid)
{
    #pragma unroll
    for (int h = 0; h < 2; ++h) {
        const int f  = h * 512 + tid;        // fragment id 0..1023
        const int tt = f >> 8;               // tile within round
        const int dt = (f >> 6) & 3;         // d-block
        const int l  = f & 63;               // fragment lane
        const int code = (Tbase + tt) * 16 + (l & 15);
        const int d0   = dt * 32 + ((l >> 4) & 3) * 8;
        const float* src = emb + (size_t)code * D_DIM + d0;
        const f32x4 a = *(const f32x4*)(src);
        const f32x4 b = *(const f32x4*)(src + 4);
        u16x8 o;
        o[0] = f2bf(a[0]); o[1] = f2bf(a[1]); o[2] = f2bf(a[2]); o[3] = f2bf(a[3]);
        o[4] = f2bf(b[0]); o[5] = f2bf(b[1]); o[6] = f2bf(b[2]); o[7] = f2bf(b[3]);
        *(u16x8*)(dst + (size_t)f * 8) = o;
    }
}

__global__ __launch_bounds__(512, 2) void vq_fused(
    const float* __restrict__ z_e,
    const float* __restrict__ emb,
    float* __restrict__ out)
{
#pragma clang fp contract(off)
    __shared__ float s_zT[PXB][ZLD];                          // 67584 B fp32 z, [px][d]
    __shared__ alignas(16) unsigned short e_s[2][TPR * 2048]; // 32768 B frag dbuf
    __shared__ float snorm[K_CODES];                          // 4096 B
    __shared__ int   s_kwin[PXB];                             // 512 B
    // total 104,960 B declared — R8's proven no-spill RA regime

    const int px  = threadIdx.x;                // lane 0..63
    const int ky  = threadIdx.y;                // wave 0..7
    const int tid = ky * 64 + px;

    const int p0  = blockIdx.x * PXB;
    const int b   = p0 >> 10;
    const int hw0 = p0 & (HW_SZ - 1);
    const float* zbase = z_e + (size_t)b * (D_DIM * HW_SZ) + hw0;

    // ---- z stage: global [d][128 px] -> s_zT[px][d] (transpose) ----
    #pragma unroll
    for (int r = 0; r < 8; ++r) {
        const int idx = r * 512 + tid;          // 0..4095
        const int d   = idx >> 5;               // 0..127
        const int i4  = (idx & 31) * 4;         // pixel group
        const f32x4 v = *(const f32x4*)(zbase + (size_t)d * HW_SZ + i4);
        s_zT[i4 + 0][d] = v[0];
        s_zT[i4 + 1][d] = v[1];
        s_zT[i4 + 2][d] = v[2];
        s_zT[i4 + 3][d] = v[3];
    }

    // ---- C_k = np.sum(emb*emb,-1): pairwise-8 (n=128), chain verbatim ----
    for (int k = tid; k < K_CODES; k += NW * 64) {
        const float* row = emb + (size_t)k * D_DIM;
        float r[8];
        #pragma unroll
        for (int j = 0; j < 8; ++j) r[j] = fmul_x(row[j], row[j]);
        for (int i = 8; i < D_DIM; i += 8) {
            #pragma unroll
            for (int j = 0; j < 8; ++j)
                r[j] = fadd_x(r[j], fmul_x(row[i + j], row[i + j]));
        }
        const float s01 = fadd_x(r[0], r[1]), s23 = fadd_x(r[2], r[3]);
        const float s45 = fadd_x(r[4], r[5]), s67 = fadd_x(r[6], r[7]);
        snorm[k] = fadd_x(fadd_x(s01, s23), fadd_x(s45, s67));
    }

    // ---- round-0 e-frags ----
    stage_tiles(emb, e_s[0], 0, tid);
    __syncthreads();                            // z + snorm + round-0 frags visible

    // ---- build A-frags: wave ky owns px rows [ky*16, ky*16+16) ----
    const int lm = px & 15;                     // 16-index (A row / B col)
    const int lg = px >> 4;                     // d-slice group 0..3
    const int pxbase = ky * 16;

    s16x8 afr[4];
    #pragma unroll
    for (int dt = 0; dt < 4; ++dt) {
        const float* zr = &s_zT[pxbase + lm][dt * 32 + lg * 8];
        const f32x4 z0 = *(const f32x4*)zr;
        const f32x4 z1 = *(const f32x4*)(zr + 4);
        s16x8 a;
        a[0] = (short)f2bf(z0[0]); a[1] = (short)f2bf(z0[1]);
        a[2] = (short)f2bf(z0[2]); a[3] = (short)f2bf(z0[3]);
        a[4] = (short)f2bf(z1[0]); a[5] = (short)f2bf(z1[1]);
        a[6] = (short)f2bf(z1[2]); a[7] = (short)f2bf(z1[3]);
        afr[dt] = a;
    }

    // per-(px-row, column) 4-deep sorted top lists, packed u32 (key|code)
    unsigned pk[4][4];
    #pragma unroll
    for (int r = 0; r < 4; ++r) {
        #pragma unroll
        for (int s = 0; s < 4; ++s) pk[r][s] = 0xFFFFFFFFu;
    }

    // ====== single coarse pass: MFMA scores + branchless selection ======
    {
        int buf = 0;
        #pragma unroll 1
        for (int rnd = 0; rnd < ROUNDS; ++rnd) {
            if (rnd + 1 < ROUNDS)
                stage_tiles(emb, e_s[buf ^ 1], (rnd + 1) * TPR, tid);
            #pragma unroll
            for (int tl = 0; tl < TPR; ++tl) {
                const unsigned short* fb = e_s[buf] + (size_t)tl * 2048 + (size_t)px * 8;
                const s16x8 c0 = *(const s16x8*)(fb);
                const s16x8 c1 = *(const s16x8*)(fb + 512);
                const s16x8 c2 = *(const s16x8*)(fb + 1024);
                const s16x8 c3 = *(const s16x8*)(fb + 1536);
                f32x4 a0 = {0.f, 0.f, 0.f, 0.f};
                f32x4 a1 = {0.f, 0.f, 0.f, 0.f};
                a0 = __builtin_amdgcn_mfma_f32_16x16x32_bf16(afr[0], c0, a0, 0, 0, 0);
                a0 = __builtin_amdgcn_mfma_f32_16x16x32_bf16(afr[1], c1, a0, 0, 0, 0);
                a1 = __builtin_amdgcn_mfma_f32_16x16x32_bf16(afr[2], c2, a1, 0, 0, 0);
                a1 = __builtin_amdgcn_mfma_f32_16x16x32_bf16(afr[3], c3, a1, 0, 0, 0);
                const int code = (rnd * TPR + tl) * 16 + lm;
                const float sn = snorm[code];
                #pragma unroll
                for (int r = 0; r < 4; ++r) {
                    const float t = fmaf(-2.f, a0[r] + a1[r], sn);
                    const unsigned p = (key32(t) & KMASK) | (unsigned)code;
                    // branchless sorted insert (bubble network, ascending)
                    const unsigned m0 = min(pk[r][0], p), M0 = max(pk[r][0], p);
                    pk[r][0] = m0;
                    const unsigned m1 = min(pk[r][1], M0), M1 = max(pk[r][1], M0);
                    pk[r][1] = m1;
                    const unsigned m2 = min(pk[r][2], M1), M2 = max(pk[r][2], M1);
                    pk[r][2] = m2;
                    pk[r][3] = min(pk[r][3], M2);
                }
            }
            __syncthreads();                    // next buf staged; this buf free
            buf ^= 1;
        }
    }

    // ---- per-row threshold keys via 16-lane shfl min (masks stay in-group) ----
    unsigned thrk[4];
    #pragma unroll
    for (int r = 0; r < 4; ++r) {
        unsigned g = pk[r][0];
        #pragma unroll
        for (int mask = 1; mask < 16; mask <<= 1) {
            const unsigned o = (unsigned)__shfl_xor((int)g, mask, 64);
            g = min(g, o);
        }
        const float tlo = unkey32(g & KMASK);   // best-t lower bound
        thrk[r] = key32(tlo + MARGIN) & KMASK;  // window threshold in key space
    }

    // ---- per-lane exact refinement of qualifying candidates + u64 combine ----
    #pragma unroll
    for (int r = 0; r < 4; ++r) {
        const int prow = pxbase + lg * 4 + r;
        unsigned long long packq = ~0ULL;
        const bool any = ((pk[r][0] & KMASK) <= thrk[r]) |
                         ((pk[r][1] & KMASK) <= thrk[r]) |
                         ((pk[r][2] & KMASK) <= thrk[r]) |
                         ((pk[r][3] & KMASK) <= thrk[r]);
        if (any) {
            // A: sequential over d (chain kept honest; value cancels per-pixel).
            const float z0 = s_zT[prow][0];
            float A32 = fmul_x(z0, z0);
            for (int d = 1; d < D_DIM; ++d) {
                const float zd = s_zT[prow][d];
                A32 = fadd_x(A32, fmul_x(zd, zd));
            }
            #pragma unroll
            for (int s = 0; s < 4; ++s) {
                if ((pk[r][s] & KMASK) <= thrk[r]) {
                    const int kc = (int)(pk[r][s] & 1023u);
                    const float* e = emb + (size_t)kc * D_DIM;
                    // B: GEMM-style single-accumulator SEQUENTIAL FMA over d.
                    float B32 = 0.f;
                    for (int d = 0; d < D_DIM; ++d)
                        B32 = ffma_x(s_zT[prow][d], e[d], B32);
                    const float twoB = fmul_x(2.0f, B32);      // exact
                    const float q    = fadd_x(fsub_x(A32, twoB), snorm[kc]);
                    // q = ||z-e||^2 ~ ||z||^2 > 0: positive-float uint order OK.
                    const unsigned long long p =
                        ((unsigned long long)__float_as_uint(q) << 32) |
                        (unsigned)kc;          // low bits = k: first-index tie-break
                    packq = (p < packq) ? p : packq;
                }
            }
        }
        // convergent 16-lane min-combine of packed (q,k)
        #pragma unroll
        for (int mask = 1; mask < 16; mask <<= 1) {
            const unsigned long long o = __shfl_xor(packq, mask, 64);
            packq = (o < packq) ? o : packq;
        }
        if (lm == 0) s_kwin[prow] = (int)(packq & 0xffffffffu);
    }
    __syncthreads();

    // ---- epilogue: out0 = fl(fl(e-z)+z) (pinned), out1 = e ----
    const int p  = tid & 127;                   // pixel
    const int dg = tid >> 7;                    // d-quarter 0..3
    const int kwin = s_kwin[p];
    const float* er = emb + (size_t)kwin * D_DIM + dg * 32;
    float* o0 = out + (size_t)b * (D_DIM * HW_SZ) + hw0 + p;
    float* o1 = o0 + OUT_OFF;
    #pragma unroll
    for (int i = 0; i < 8; ++i) {
        const f32x4 e4 = *(const f32x4*)(er + i * 4);
        #pragma unroll
        for (int j = 0; j < 4; ++j) {
            const int d = dg * 32 + i * 4 + j;
            const float zv = s_zT[p][d];
            o0[(size_t)d * HW_SZ] = fadd_x(fsub_x(e4[j], zv), zv);
            o1[(size_t)d * HW_SZ] = e4[j];
        }
    }
}

extern "C" void kernel_launch(void* const* d_in, const int* in_sizes, int n_in,
                              void* d_out, int out_size, void* d_ws, size_t ws_size,
                              hipStream_t stream)
{
    const float* z_e = (const float*)d_in[0];
    const float* emb = (const float*)d_in[1];
    float* out = (float*)d_out;
    (void)in_sizes; (void)n_in; (void)out_size; (void)d_ws; (void)ws_size;

    vq_fused<<<dim3(N_PIX / PXB), dim3(64, NW), 0, stream>>>(z_e, emb, out);
}

// Round 13
// 317.311 us; speedup vs baseline: 2.9426x; 1.6589x over previous
//
#include <hip/hip_runtime.h>
#include <cmath>

// VQ-VAE quantization forward: B=64, K=1024, D=128, H=W=32.
// Ref model (6 rounds of absmax triangulation): q_k = fl32(fl32(A - fl32(2*B_k)) + C_k),
// first-index argmin, B = single-accumulator SEQUENTIAL FMA over d.
// A = sum(z*z,-1) sequential; C = sum(emb*emb,-1) pairwise-8.
// out0 = fl(fl(e-z)+z); out1 = e. Exact chains pinned with empty-asm barriers.
//
// R13 = R12 (473us dispatch, branchless selection, big-LDS no-spill regime)
// with two targeted latency fixes:
//  * snorm PRECOMPUTED once by a prologue kernel (verbatim pinned pairwise-8
//    chain => bit-identical) into d_ws; main kernel loads it coalesced.
//    Removes per-block redundant recompute: 256 uncoalesced scalar-chain
//    loads/thread whose 64-distinct-line splits serialize the L1 port
//    (~30-40K cyc/block) in all 512 blocks.
//  * Staging split per T14 (issue-early/write-late): stage_load issues the 4
//    global f32x4 at round start; the round's 16 MFMAs + selection run under
//    the load latency; stage_write (f2bf + ds_write) lands after compute,
//    before the barrier. Removes the per-round full-latency drain that
//    stage_tiles' load->write back-to-back forced.
// Verbatim from R12: s_zT transpose, fragment bijection (l&15=code,
// l>>4=d-slice), C/D map col=lane&15(code) row=(lane>>4)*4+reg(px), f2bf bits,
// branchless packed-u32 top-4 selection (KMASK truncation << MARGIN), 16-lane
// shfl threshold, exact pinned A/B/epilogue chains, packed (q,k) u64
// min-combine, first-index tie-break.

#define D_DIM   128
#define K_CODES 1024
#define HW_SZ   1024
#define N_PIX   65536
#define OUT_OFF ((size_t)N_PIX * D_DIM)

#define PXB     128                     // pixels per block
#define NW      8                       // waves per block
#define NTILE   (K_CODES / 16)          // 64 code-tiles
#define TPR     4                       // tiles staged per round
#define ROUNDS  (NTILE / TPR)           // 16
#define ZLD     132                     // padded z row (floats)
#define MARGIN  2.0e-3f                 // coarse->exact window
#define KMASK   0xFFFFFC00u             // key bits (code in low 10)

typedef float  f32x4 __attribute__((ext_vector_type(4)));
typedef short  s16x8 __attribute__((ext_vector_type(8)));
typedef unsigned short u16x8 __attribute__((ext_vector_type(8)));

// --- compiler-proof fp32 ops: result pinned in a VGPR via empty asm ---
__device__ __forceinline__ float fmul_x(float a, float b) {
    float r = a * b; asm volatile("" : "+v"(r)); return r;
}
__device__ __forceinline__ float fadd_x(float a, float b) {
    float r = a + b; asm volatile("" : "+v"(r)); return r;
}
__device__ __forceinline__ float fsub_x(float a, float b) {
    float r = a - b; asm volatile("" : "+v"(r)); return r;
}
__device__ __forceinline__ float ffma_x(float a, float b, float c) {
    float r = fmaf(a, b, c); asm volatile("" : "+v"(r)); return r;
}

// RNE float -> bf16 bits (inputs are normal floats here)
__device__ __forceinline__ unsigned short f2bf(float f) {
    unsigned u = __float_as_uint(f);
    u += 0x7FFFu + ((u >> 16) & 1u);
    return (unsigned short)(u >> 16);
}

// monotone float<->u32 order-preserving transform (no NaNs in play)
__device__ __forceinline__ unsigned key32(float t) {
    const unsigned u = __float_as_uint(t);
    return u ^ (unsigned)(((int)u >> 31) | (int)0x80000000);
}
__device__ __forceinline__ float unkey32(unsigned k) {
    const unsigned u = (k & 0x80000000u) ? (k ^ 0x80000000u) : ~k;
    return __uint_as_float(u);
}

// ---- prologue: snorm table, pairwise-8 pinned chain VERBATIM, once ----
__global__ __launch_bounds__(256) void snorm_pre(
    const float* __restrict__ emb, float* __restrict__ ws)
{
#pragma clang fp contract(off)
    const int k = blockIdx.x * 256 + threadIdx.x;   // 0..1023
    const float* row = emb + (size_t)k * D_DIM;
    float r[8];
    #pragma unroll
    for (int j = 0; j < 8; ++j) r[j] = fmul_x(row[j], row[j]);
    for (int i = 8; i < D_DIM; i += 8) {
        #pragma unroll
        for (int j = 0; j < 8; ++j)
            r[j] = fadd_x(r[j], fmul_x(row[i + j], row[i + j]));
    }
    const float s01 = fadd_x(r[0], r[1]), s23 = fadd_x(r[2], r[3]);
    const float s45 = fadd_x(r[4], r[5]), s67 = fadd_x(r[6], r[7]);
    ws[k] = fadd_x(fadd_x(s01, s23), fadd_x(s45, s67));
}

// fragment geometry for lane f (0..1023): tile tt, d-block dt, frag-lane l
__device__ __forceinline__ const float* frag_src(
    const float* __restrict__ emb, const int Tbase, const int f)
{
    const int tt = f >> 8;
    const int dt = (f >> 6) & 3;
    const int l  = f & 63;
    const int code = (Tbase + tt) * 16 + (l & 15);
    const int d0   = dt * 32 + ((l >> 4) & 3) * 8;
    return emb + (size_t)code * D_DIM + d0;
}

__global__ __launch_bounds__(512, 2) void vq_fused(
    const float* __restrict__ z_e,
    const float* __restrict__ emb,
    const float* __restrict__ sn_ws,
    float* __restrict__ out)
{
#pragma clang fp contract(off)
    __shared__ float s_zT[PXB][ZLD];                          // 67584 B fp32 z, [px][d]
    __shared__ alignas(16) unsigned short e_s[2][TPR * 2048]; // 32768 B frag dbuf
    __shared__ float snorm[K_CODES];                          // 4096 B
    __shared__ int   s_kwin[PXB];                             // 512 B
    // total 104,960 B declared — R8/R12's proven no-spill RA regime

    const int px  = threadIdx.x;                // lane 0..63
    const int ky  = threadIdx.y;                // wave 0..7
    const int tid = ky * 64 + px;

    const int p0  = blockIdx.x * PXB;
    const int b   = p0 >> 10;
    const int hw0 = p0 & (HW_SZ - 1);
    const float* zbase = z_e + (size_t)b * (D_DIM * HW_SZ) + hw0;

    // ---- snorm: coalesced load of the precomputed table (identical bits) ----
    snorm[tid]       = sn_ws[tid];
    snorm[tid + 512] = sn_ws[tid + 512];

    // ---- z stage: global [d][128 px] -> s_zT[px][d] (transpose) ----
    #pragma unroll
    for (int r = 0; r < 8; ++r) {
        const int idx = r * 512 + tid;          // 0..4095
        const int d   = idx >> 5;               // 0..127
        const int i4  = (idx & 31) * 4;         // pixel group
        const f32x4 v = *(const f32x4*)(zbase + (size_t)d * HW_SZ + i4);
        s_zT[i4 + 0][d] = v[0];
        s_zT[i4 + 1][d] = v[1];
        s_zT[i4 + 2][d] = v[2];
        s_zT[i4 + 3][d] = v[3];
    }

    // ---- round-0 e-frags (load + write together; nothing to overlap yet) ----
    {
        f32x4 va0 = *(const f32x4*)(frag_src(emb, 0, tid));
        f32x4 va1 = *(const f32x4*)(frag_src(emb, 0, tid) + 4);
        f32x4 vb0 = *(const f32x4*)(frag_src(emb, 0, 512 + tid));
        f32x4 vb1 = *(const f32x4*)(frag_src(emb, 0, 512 + tid) + 4);
        u16x8 o;
        o[0] = f2bf(va0[0]); o[1] = f2bf(va0[1]); o[2] = f2bf(va0[2]); o[3] = f2bf(va0[3]);
        o[4] = f2bf(va1[0]); o[5] = f2bf(va1[1]); o[6] = f2bf(va1[2]); o[7] = f2bf(va1[3]);
        *(u16x8*)(e_s[0] + (size_t)tid * 8) = o;
        o[0] = f2bf(vb0[0]); o[1] = f2bf(vb0[1]); o[2] = f2bf(vb0[2]); o[3] = f2bf(vb0[3]);
        o[4] = f2bf(vb1[0]); o[5] = f2bf(vb1[1]); o[6] = f2bf(vb1[2]); o[7] = f2bf(vb1[3]);
        *(u16x8*)(e_s[0] + (size_t)(512 + tid) * 8) = o;
    }
    __syncthreads();                            // z + snorm + round-0 frags visible

    // ---- build A-frags: wave ky owns px rows [ky*16, ky*16+16) ----
    const int lm = px & 15;                     // 16-index (A row / B col)
    const int lg = px >> 4;                     // d-slice group 0..3
    const int pxbase = ky * 16;

    s16x8 afr[4];
    #pragma unroll
    for (int dt = 0; dt < 4; ++dt) {
        const float* zr = &s_zT[pxbase + lm][dt * 32 + lg * 8];
        const f32x4 z0 = *(const f32x4*)zr;
        const f32x4 z1 = *(const f32x4*)(zr + 4);
        s16x8 a;
        a[0] = (short)f2bf(z0[0]); a[1] = (short)f2bf(z0[1]);
        a[2] = (short)f2bf(z0[2]); a[3] = (short)f2bf(z0[3]);
        a[4] = (short)f2bf(z1[0]); a[5] = (short)f2bf(z1[1]);
        a[6] = (short)f2bf(z1[2]); a[7] = (short)f2bf(z1[3]);
        afr[dt] = a;
    }

    // per-(px-row, column) 4-deep sorted top lists, packed u32 (key|code)
    unsigned pk[4][4];
    #pragma unroll
    for (int r = 0; r < 4; ++r) {
        #pragma unroll
        for (int s = 0; s < 4; ++s) pk[r][s] = 0xFFFFFFFFu;
    }

    // ====== coarse pass: T14-split staging + MFMA + branchless selection ======
    {
        int buf = 0;
        #pragma unroll 1
        for (int rnd = 0; rnd < ROUNDS; ++rnd) {
            // (a) ISSUE next round's global loads (latency hides under compute)
            f32x4 va0, va1, vb0, vb1;
            const bool pre = (rnd + 1 < ROUNDS);
            if (pre) {
                const float* sa = frag_src(emb, (rnd + 1) * TPR, tid);
                const float* sb = frag_src(emb, (rnd + 1) * TPR, 512 + tid);
                va0 = *(const f32x4*)(sa);
                va1 = *(const f32x4*)(sa + 4);
                vb0 = *(const f32x4*)(sb);
                vb1 = *(const f32x4*)(sb + 4);
            }
            // (b) compute current round from e_s[buf]
            #pragma unroll
            for (int tl = 0; tl < TPR; ++tl) {
                const unsigned short* fb = e_s[buf] + (size_t)tl * 2048 + (size_t)px * 8;
                const s16x8 c0 = *(const s16x8*)(fb);
                const s16x8 c1 = *(const s16x8*)(fb + 512);
                const s16x8 c2 = *(const s16x8*)(fb + 1024);
                const s16x8 c3 = *(const s16x8*)(fb + 1536);
                f32x4 a0 = {0.f, 0.f, 0.f, 0.f};
                f32x4 a1 = {0.f, 0.f, 0.f, 0.f};
                a0 = __builtin_amdgcn_mfma_f32_16x16x32_bf16(afr[0], c0, a0, 0, 0, 0);
                a0 = __builtin_amdgcn_mfma_f32_16x16x32_bf16(afr[1], c1, a0, 0, 0, 0);
                a1 = __builtin_amdgcn_mfma_f32_16x16x32_bf16(afr[2], c2, a1, 0, 0, 0);
                a1 = __builtin_amdgcn_mfma_f32_16x16x32_bf16(afr[3], c3, a1, 0, 0, 0);
                const int code = (rnd * TPR + tl) * 16 + lm;
                const float sn = snorm[code];
                #pragma unroll
                for (int r = 0; r < 4; ++r) {
                    const float t = fmaf(-2.f, a0[r] + a1[r], sn);
                    const unsigned p = (key32(t) & KMASK) | (unsigned)code;
                    // branchless sorted insert (bubble network, ascending)
                    const unsigned m0 = min(pk[r][0], p), M0 = max(pk[r][0], p);
                    pk[r][0] = m0;
                    const unsigned m1 = min(pk[r][1], M0), M1 = max(pk[r][1], M0);
                    pk[r][1] = m1;
                    const unsigned m2 = min(pk[r][2], M1), M2 = max(pk[r][2], M1);
                    pk[r][2] = m2;
                    pk[r][3] = min(pk[r][3], M2);
                }
            }
            // (c) WRITE the prefetched frags (vmcnt waits land here, post-compute)
            if (pre) {
                u16x8 o;
                o[0] = f2bf(va0[0]); o[1] = f2bf(va0[1]); o[2] = f2bf(va0[2]); o[3] = f2bf(va0[3]);
                o[4] = f2bf(va1[0]); o[5] = f2bf(va1[1]); o[6] = f2bf(va1[2]); o[7] = f2bf(va1[3]);
                *(u16x8*)(e_s[buf ^ 1] + (size_t)tid * 8) = o;
                o[0] = f2bf(vb0[0]); o[1] = f2bf(vb0[1]); o[2] = f2bf(vb0[2]); o[3] = f2bf(vb0[3]);
                o[4] = f2bf(vb1[0]); o[5] = f2bf(vb1[1]); o[6] = f2bf(vb1[2]); o[7] = f2bf(vb1[3]);
                *(u16x8*)(e_s[buf ^ 1] + (size_t)(512 + tid) * 8) = o;
            }
            __syncthreads();                    // next buf staged; this buf free
            buf ^= 1;
        }
    }

    // ---- per-row threshold keys via 16-lane shfl min (masks stay in-group) ----
    unsigned thrk[4];
    #pragma unroll
    for (int r = 0; r < 4; ++r) {
        unsigned g = pk[r][0];
        #pragma unroll
        for (int mask = 1; mask < 16; mask <<= 1) {
            const unsigned o = (unsigned)__shfl_xor((int)g, mask, 64);
            g = min(g, o);
        }
        const float tlo = unkey32(g & KMASK);   // best-t lower bound
        thrk[r] = key32(tlo + MARGIN) & KMASK;  // window threshold in key space
    }

    // ---- per-lane exact refinement of qualifying candidates + u64 combine ----
    #pragma unroll
    for (int r = 0; r < 4; ++r) {
        const int prow = pxbase + lg * 4 + r;
        unsigned long long packq = ~0ULL;
        const bool any = ((pk[r][0] & KMASK) <= thrk[r]) |
                         ((pk[r][1] & KMASK) <= thrk[r]) |
                         ((pk[r][2] & KMASK) <= thrk[r]) |
                         ((pk[r][3] & KMASK) <= thrk[r]);
        if (any) {
            // A: sequential over d (chain kept honest; value cancels per-pixel).
            const float z0 = s_zT[prow][0];
            float A32 = fmul_x(z0, z0);
            for (int d = 1; d < D_DIM; ++d) {
                const float zd = s_zT[prow][d];
                A32 = fadd_x(A32, fmul_x(zd, zd));
            }
            #pragma unroll
            for (int s = 0; s < 4; ++s) {
                if ((pk[r][s] & KMASK) <= thrk[r]) {
                    const int kc = (int)(pk[r][s] & 1023u);
                    const float* e = emb + (size_t)kc * D_DIM;
                    // B: GEMM-style single-accumulator SEQUENTIAL FMA over d.
                    float B32 = 0.f;
                    for (int d = 0; d < D_DIM; ++d)
                        B32 = ffma_x(s_zT[prow][d], e[d], B32);
                    const float twoB = fmul_x(2.0f, B32);      // exact
                    const float q    = fadd_x(fsub_x(A32, twoB), snorm[kc]);
                    // q = ||z-e||^2 ~ ||z||^2 > 0: positive-float uint order OK.
                    const unsigned long long p =
                        ((unsigned long long)__float_as_uint(q) << 32) |
                        (unsigned)kc;          // low bits = k: first-index tie-break
                    packq = (p < packq) ? p : packq;
                }
            }
        }
        // convergent 16-lane min-combine of packed (q,k)
        #pragma unroll
        for (int mask = 1; mask < 16; mask <<= 1) {
            const unsigned long long o = __shfl_xor(packq, mask, 64);
            packq = (o < packq) ? o : packq;
        }
        if (lm == 0) s_kwin[prow] = (int)(packq & 0xffffffffu);
    }
    __syncthreads();

    // ---- epilogue: out0 = fl(fl(e-z)+z) (pinned), out1 = e ----
    const int p  = tid & 127;                   // pixel
    const int dg = tid >> 7;                    // d-quarter 0..3
    const int kwin = s_kwin[p];
    const float* er = emb + (size_t)kwin * D_DIM + dg * 32;
    float* o0 = out + (size_t)b * (D_DIM * HW_SZ) + hw0 + p;
    float* o1 = o0 + OUT_OFF;
    #pragma unroll
    for (int i = 0; i < 8; ++i) {
        const f32x4 e4 = *(const f32x4*)(er + i * 4);
        #pragma unroll
        for (int j = 0; j < 4; ++j) {
            const int d = dg * 32 + i * 4 + j;
            const float zv = s_zT[p][d];
            o0[(size_t)d * HW_SZ] = fadd_x(fsub_x(e4[j], zv), zv);
            o1[(size_t)d * HW_SZ] = e4[j];
        }
    }
}

extern "C" void kernel_launch(void* const* d_in, const int* in_sizes, int n_in,
                              void* d_out, int out_size, void* d_ws, size_t ws_size,
                              hipStream_t stream)
{
    const float* z_e = (const float*)d_in[0];
    const float* emb = (const float*)d_in[1];
    float* out = (float*)d_out;
    float* sn_ws = (float*)d_ws;
    (void)in_sizes; (void)n_in; (void)out_size; (void)ws_size;

    snorm_pre<<<dim3(K_CODES / 256), dim3(256), 0, stream>>>(emb, sn_ws);
    vq_fused<<<dim3(N_PIX / PXB), dim3(64, NW), 0, stream>>>(z_e, emb, sn_ws, out);
}

// Round 14
// 293.195 us; speedup vs baseline: 3.1847x; 1.0823x over previous
//
#include <hip/hip_runtime.h>
#include <cmath>

// VQ-VAE quantization forward: B=64, K=1024, D=128, H=W=32.
// Ref model (6 rounds of absmax triangulation): q_k = fl32(fl32(A - fl32(2*B_k)) + C_k),
// first-index argmin, B = single-accumulator SEQUENTIAL FMA over d.
// A = sum(z*z,-1) sequential; C = sum(emb*emb,-1) pairwise-8.
// out0 = fl(fl(e-z)+z); out1 = e. Exact chains pinned with empty-asm barriers.
//
// R14 = R13 (238us dispatch) widened to 16 waves/block (1024 threads) in the
// SAME ~105KB big-LDS no-spill regime. R13 was latency-bound at 2 waves/SIMD
// (all pipes <=20% busy, occupancy 20%): every ds_read->MFMA dep, selection
// chain, and barrier join was wall-clock. 1024-thread blocks at 1 block/CU
// force VGPR<=128 as a hard launchability constraint (4 waves/SIMD x 128 =
// 512-reg file) — measured live set is 88 <= 128, so no spill is required —
// and double the latency-hiding waves 2->4 per SIMD.
//  * wave-half h=ky>>3 computes tiles {2h,2h+1} per round: per-wave MFMA +
//    selection halves; staging = 1 frag/thread/round.
//  * top-4 per (column, half) partition is FINER than per-column => kept
//    candidates are a SUPERSET of R13's; gmin over the same 1024 bitwise-
//    identical t values; exact chains + tie-break verbatim => absmax 0.
//  * cross-half combine via plain LDS slots (s_gmin[2][128], s_pk64[2][128]),
//    no atomics, one barrier each.
// Verbatim from R13: snorm prologue (pinned pairwise-8), T14 split staging,
// s_zT transpose, fragment bijection, C/D map, f2bf bits, branchless packed
// u32 selection (KMASK truncation << MARGIN), exact pinned A/B/epilogue
// chains, packed (q,k) u64 min, first-index tie-break.

#define D_DIM   128
#define K_CODES 1024
#define HW_SZ   1024
#define N_PIX   65536
#define OUT_OFF ((size_t)N_PIX * D_DIM)

#define PXB     128                     // pixels per block
#define NW      16                      // waves per block (1024 threads)
#define NTILE   (K_CODES / 16)          // 64 code-tiles
#define TPR     4                       // tiles staged per round
#define ROUNDS  (NTILE / TPR)           // 16
#define ZLD     132                     // padded z row (floats)
#define MARGIN  2.0e-3f                 // coarse->exact window
#define KMASK   0xFFFFFC00u             // key bits (code in low 10)

typedef float  f32x4 __attribute__((ext_vector_type(4)));
typedef short  s16x8 __attribute__((ext_vector_type(8)));
typedef unsigned short u16x8 __attribute__((ext_vector_type(8)));

// --- compiler-proof fp32 ops: result pinned in a VGPR via empty asm ---
__device__ __forceinline__ float fmul_x(float a, float b) {
    float r = a * b; asm volatile("" : "+v"(r)); return r;
}
__device__ __forceinline__ float fadd_x(float a, float b) {
    float r = a + b; asm volatile("" : "+v"(r)); return r;
}
__device__ __forceinline__ float fsub_x(float a, float b) {
    float r = a - b; asm volatile("" : "+v"(r)); return r;
}
__device__ __forceinline__ float ffma_x(float a, float b, float c) {
    float r = fmaf(a, b, c); asm volatile("" : "+v"(r)); return r;
}

// RNE float -> bf16 bits (inputs are normal floats here)
__device__ __forceinline__ unsigned short f2bf(float f) {
    unsigned u = __float_as_uint(f);
    u += 0x7FFFu + ((u >> 16) & 1u);
    return (unsigned short)(u >> 16);
}

// monotone float<->u32 order-preserving transform (no NaNs in play)
__device__ __forceinline__ unsigned key32(float t) {
    const unsigned u = __float_as_uint(t);
    return u ^ (unsigned)(((int)u >> 31) | (int)0x80000000);
}
__device__ __forceinline__ float unkey32(unsigned k) {
    const unsigned u = (k & 0x80000000u) ? (k ^ 0x80000000u) : ~k;
    return __uint_as_float(u);
}

// ---- prologue: snorm table, pairwise-8 pinned chain VERBATIM, once ----
__global__ __launch_bounds__(256) void snorm_pre(
    const float* __restrict__ emb, float* __restrict__ ws)
{
#pragma clang fp contract(off)
    const int k = blockIdx.x * 256 + threadIdx.x;   // 0..1023
    const float* row = emb + (size_t)k * D_DIM;
    float r[8];
    #pragma unroll
    for (int j = 0; j < 8; ++j) r[j] = fmul_x(row[j], row[j]);
    for (int i = 8; i < D_DIM; i += 8) {
        #pragma unroll
        for (int j = 0; j < 8; ++j)
            r[j] = fadd_x(r[j], fmul_x(row[i + j], row[i + j]));
    }
    const float s01 = fadd_x(r[0], r[1]), s23 = fadd_x(r[2], r[3]);
    const float s45 = fadd_x(r[4], r[5]), s67 = fadd_x(r[6], r[7]);
    ws[k] = fadd_x(fadd_x(s01, s23), fadd_x(s45, s67));
}

// fragment geometry for frag id f (0..1023): tile tt, d-block dt, frag-lane l
__device__ __forceinline__ const float* frag_src(
    const float* __restrict__ emb, const int Tbase, const int f)
{
    const int tt = f >> 8;
    const int dt = (f >> 6) & 3;
    const int l  = f & 63;
    const int code = (Tbase + tt) * 16 + (l & 15);
    const int d0   = dt * 32 + ((l >> 4) & 3) * 8;
    return emb + (size_t)code * D_DIM + d0;
}

__global__ __launch_bounds__(1024) void vq_fused(
    const float* __restrict__ z_e,
    const float* __restrict__ emb,
    const float* __restrict__ sn_ws,
    float* __restrict__ out)
{
#pragma clang fp contract(off)
    __shared__ float s_zT[PXB][ZLD];                          // 67584 B fp32 z, [px][d]
    __shared__ alignas(16) unsigned short e_s[2][TPR * 2048]; // 32768 B frag dbuf
    __shared__ float snorm[K_CODES];                          // 4096 B
    __shared__ unsigned s_gmin[2][PXB];                       // 1024 B per-half row mins
    __shared__ unsigned long long s_pk64[2][PXB];             // 2048 B per-half (q,k)
    __shared__ int s_kwin[PXB];                               // 512 B
    // total ~108 KB => 1 block/CU, big-LDS RA regime; 1024 thr forces VGPR<=128

    const int px  = threadIdx.x;                // lane 0..63
    const int ky  = threadIdx.y;                // wave 0..15
    const int tid = ky * 64 + px;               // 0..1023

    const int p0  = blockIdx.x * PXB;
    const int b   = p0 >> 10;
    const int hw0 = p0 & (HW_SZ - 1);
    const float* zbase = z_e + (size_t)b * (D_DIM * HW_SZ) + hw0;

    // ---- snorm: coalesced load of the precomputed table (identical bits) ----
    snorm[tid] = sn_ws[tid];

    // ---- z stage: global [d][128 px] -> s_zT[px][d] (transpose) ----
    #pragma unroll
    for (int r = 0; r < 4; ++r) {
        const int idx = r * 1024 + tid;         // 0..4095
        const int d   = idx >> 5;               // 0..127
        const int i4  = (idx & 31) * 4;         // pixel group
        const f32x4 v = *(const f32x4*)(zbase + (size_t)d * HW_SZ + i4);
        s_zT[i4 + 0][d] = v[0];
        s_zT[i4 + 1][d] = v[1];
        s_zT[i4 + 2][d] = v[2];
        s_zT[i4 + 3][d] = v[3];
    }

    // ---- round-0 e-frags: exactly one frag per thread ----
    {
        const float* s = frag_src(emb, 0, tid);
        const f32x4 va0 = *(const f32x4*)(s);
        const f32x4 va1 = *(const f32x4*)(s + 4);
        u16x8 o;
        o[0] = f2bf(va0[0]); o[1] = f2bf(va0[1]); o[2] = f2bf(va0[2]); o[3] = f2bf(va0[3]);
        o[4] = f2bf(va1[0]); o[5] = f2bf(va1[1]); o[6] = f2bf(va1[2]); o[7] = f2bf(va1[3]);
        *(u16x8*)(e_s[0] + (size_t)tid * 8) = o;
    }
    __syncthreads();                            // z + snorm + round-0 frags visible

    // ---- build A-frags: wave (ky&7) owns px rows [(ky&7)*16, +16) ----
    const int lm = px & 15;                     // 16-index (A row / B col)
    const int lg = px >> 4;                     // d-slice group 0..3
    const int pxbase = (ky & 7) * 16;
    const int half = ky >> 3;                   // code-half within each round

    s16x8 afr[4];
    #pragma unroll
    for (int dt = 0; dt < 4; ++dt) {
        const float* zr = &s_zT[pxbase + lm][dt * 32 + lg * 8];
        const f32x4 z0 = *(const f32x4*)zr;
        const f32x4 z1 = *(const f32x4*)(zr + 4);
        s16x8 a;
        a[0] = (short)f2bf(z0[0]); a[1] = (short)f2bf(z0[1]);
        a[2] = (short)f2bf(z0[2]); a[3] = (short)f2bf(z0[3]);
        a[4] = (short)f2bf(z1[0]); a[5] = (short)f2bf(z1[1]);
        a[6] = (short)f2bf(z1[2]); a[7] = (short)f2bf(z1[3]);
        afr[dt] = a;
    }

    // per-(px-row, column, half) 4-deep sorted top lists, packed u32 (key|code)
    unsigned pk[4][4];
    #pragma unroll
    for (int r = 0; r < 4; ++r) {
        #pragma unroll
        for (int s = 0; s < 4; ++s) pk[r][s] = 0xFFFFFFFFu;
    }

    // ====== coarse pass: T14-split staging + MFMA + branchless selection ======
    {
        int buf = 0;
        #pragma unroll 1
        for (int rnd = 0; rnd < ROUNDS; ++rnd) {
            // (a) ISSUE next round's global load (1 frag/thread)
            f32x4 va0, va1;
            const bool pre = (rnd + 1 < ROUNDS);
            if (pre) {
                const float* s = frag_src(emb, (rnd + 1) * TPR, tid);
                va0 = *(const f32x4*)(s);
                va1 = *(const f32x4*)(s + 4);
            }
            // (b) compute this wave-half's 2 tiles from e_s[buf]
            #pragma unroll
            for (int ti = 0; ti < 2; ++ti) {
                const int tl = half * 2 + ti;
                const unsigned short* fb = e_s[buf] + (size_t)tl * 2048 + (size_t)px * 8;
                const s16x8 c0 = *(const s16x8*)(fb);
                const s16x8 c1 = *(const s16x8*)(fb + 512);
                const s16x8 c2 = *(const s16x8*)(fb + 1024);
                const s16x8 c3 = *(const s16x8*)(fb + 1536);
                f32x4 a0 = {0.f, 0.f, 0.f, 0.f};
                f32x4 a1 = {0.f, 0.f, 0.f, 0.f};
                a0 = __builtin_amdgcn_mfma_f32_16x16x32_bf16(afr[0], c0, a0, 0, 0, 0);
                a0 = __builtin_amdgcn_mfma_f32_16x16x32_bf16(afr[1], c1, a0, 0, 0, 0);
                a1 = __builtin_amdgcn_mfma_f32_16x16x32_bf16(afr[2], c2, a1, 0, 0, 0);
                a1 = __builtin_amdgcn_mfma_f32_16x16x32_bf16(afr[3], c3, a1, 0, 0, 0);
                const int code = (rnd * TPR + tl) * 16 + lm;
                const float sn = snorm[code];
                #pragma unroll
                for (int r = 0; r < 4; ++r) {
                    const float t = fmaf(-2.f, a0[r] + a1[r], sn);
                    const unsigned p = (key32(t) & KMASK) | (unsigned)code;
                    // branchless sorted insert (bubble network, ascending)
                    const unsigned m0 = min(pk[r][0], p), M0 = max(pk[r][0], p);
                    pk[r][0] = m0;
                    const unsigned m1 = min(pk[r][1], M0), M1 = max(pk[r][1], M0);
                    pk[r][1] = m1;
                    const unsigned m2 = min(pk[r][2], M1), M2 = max(pk[r][2], M1);
                    pk[r][2] = m2;
                    pk[r][3] = min(pk[r][3], M2);
                }
            }
            // (c) WRITE the prefetched frag (vmcnt wait lands here, post-compute)
            if (pre) {
                u16x8 o;
                o[0] = f2bf(va0[0]); o[1] = f2bf(va0[1]); o[2] = f2bf(va0[2]); o[3] = f2bf(va0[3]);
                o[4] = f2bf(va1[0]); o[5] = f2bf(va1[1]); o[6] = f2bf(va1[2]); o[7] = f2bf(va1[3]);
                *(u16x8*)(e_s[buf ^ 1] + (size_t)tid * 8) = o;
            }
            __syncthreads();                    // next buf staged; this buf free
            buf ^= 1;
        }
    }

    // ---- per-half per-row min via 16-lane shfl, then LDS slot ----
    #pragma unroll
    for (int r = 0; r < 4; ++r) {
        unsigned g = pk[r][0];
        #pragma unroll
        for (int mask = 1; mask < 16; mask <<= 1) {
            const unsigned o = (unsigned)__shfl_xor((int)g, mask, 64);
            g = min(g, o);
        }
        if (lm == 0) s_gmin[half][pxbase + lg * 4 + r] = g;
    }
    __syncthreads();

    // ---- per-row threshold from cross-half min ----
    unsigned thrk[4];
    #pragma unroll
    for (int r = 0; r < 4; ++r) {
        const int prow = pxbase + lg * 4 + r;
        const unsigned g = min(s_gmin[0][prow], s_gmin[1][prow]);
        const float tlo = unkey32(g & KMASK);   // best-t lower bound
        thrk[r] = key32(tlo + MARGIN) & KMASK;  // window threshold in key space
    }

    // ---- per-lane exact refinement of qualifying candidates + u64 combine ----
    #pragma unroll
    for (int r = 0; r < 4; ++r) {
        const int prow = pxbase + lg * 4 + r;
        unsigned long long packq = ~0ULL;
        const bool any = ((pk[r][0] & KMASK) <= thrk[r]) |
                         ((pk[r][1] & KMASK) <= thrk[r]) |
                         ((pk[r][2] & KMASK) <= thrk[r]) |
                         ((pk[r][3] & KMASK) <= thrk[r]);
        if (any) {
            // A: sequential over d (chain kept honest; value cancels per-pixel).
            const float z0 = s_zT[prow][0];
            float A32 = fmul_x(z0, z0);
            for (int d = 1; d < D_DIM; ++d) {
                const float zd = s_zT[prow][d];
                A32 = fadd_x(A32, fmul_x(zd, zd));
            }
            #pragma unroll
            for (int s = 0; s < 4; ++s) {
                if ((pk[r][s] & KMASK) <= thrk[r]) {
                    const int kc = (int)(pk[r][s] & 1023u);
                    const float* e = emb + (size_t)kc * D_DIM;
                    // B: GEMM-style single-accumulator SEQUENTIAL FMA over d.
                    float B32 = 0.f;
                    for (int d = 0; d < D_DIM; ++d)
                        B32 = ffma_x(s_zT[prow][d], e[d], B32);
                    const float twoB = fmul_x(2.0f, B32);      // exact
                    const float q    = fadd_x(fsub_x(A32, twoB), snorm[kc]);
                    // q = ||z-e||^2 ~ ||z||^2 > 0: positive-float uint order OK.
                    const unsigned long long p =
                        ((unsigned long long)__float_as_uint(q) << 32) |
                        (unsigned)kc;          // low bits = k: first-index tie-break
                    packq = (p < packq) ? p : packq;
                }
            }
        }
        // convergent 16-lane min-combine of packed (q,k)
        #pragma unroll
        for (int mask = 1; mask < 16; mask <<= 1) {
            const unsigned long long o = __shfl_xor(packq, mask, 64);
            packq = (o < packq) ? o : packq;
        }
        if (lm == 0) s_pk64[half][prow] = packq;
    }
    __syncthreads();

    // ---- cross-half final argmin ----
    if (tid < PXB) {
        const unsigned long long p0q = s_pk64[0][tid];
        const unsigned long long p1q = s_pk64[1][tid];
        s_kwin[tid] = (int)((p0q < p1q ? p0q : p1q) & 0xffffffffu);
    }
    __syncthreads();

    // ---- epilogue: out0 = fl(fl(e-z)+z) (pinned), out1 = e ----
    const int p  = tid & 127;                   // pixel
    const int dg = tid >> 7;                    // d-eighth 0..7
    const int kwin = s_kwin[p];
    const float* er = emb + (size_t)kwin * D_DIM + dg * 16;
    float* o0 = out + (size_t)b * (D_DIM * HW_SZ) + hw0 + p;
    float* o1 = o0 + OUT_OFF;
    #pragma unroll
    for (int i = 0; i < 4; ++i) {
        const f32x4 e4 = *(const f32x4*)(er + i * 4);
        #pragma unroll
        for (int j = 0; j < 4; ++j) {
            const int d = dg * 16 + i * 4 + j;
            const float zv = s_zT[p][d];
            o0[(size_t)d * HW_SZ] = fadd_x(fsub_x(e4[j], zv), zv);
            o1[(size_t)d * HW_SZ] = e4[j];
        }
    }
}

extern "C" void kernel_launch(void* const* d_in, const int* in_sizes, int n_in,
                              void* d_out, int out_size, void* d_ws, size_t ws_size,
                              hipStream_t stream)
{
    const float* z_e = (const float*)d_in[0];
    const float* emb = (const float*)d_in[1];
    float* out = (float*)d_out;
    float* sn_ws = (float*)d_ws;
    (void)in_sizes; (void)n_in; (void)out_size; (void)ws_size;

    snorm_pre<<<dim3(K_CODES / 256), dim3(256), 0, stream>>>(emb, sn_ws);
    vq_fused<<<dim3(N_PIX / PXB), dim3(64, NW), 0, stream>>>(z_e, emb, sn_ws, out);
}